// Round 20
// baseline (116.388 us; speedup 1.0000x reference)
//
#include <hip/hip_runtime.h>

// Global attention block: x(8,32,32,768) fp32 -> qkv(2304) -> 12-head attn (L=1024, hd=64) -> proj(768) fp32
// Device I/O fp32; internal compute bf16 MFMA with fp32 accumulation.

typedef __attribute__((ext_vector_type(8))) __bf16 bf16x8;
typedef __attribute__((ext_vector_type(4))) __bf16 bf16x4;
typedef __attribute__((ext_vector_type(4))) float f32x4;

#define GLL16(g, l) __builtin_amdgcn_global_load_lds( \
    (const __attribute__((address_space(1))) void*)(g), \
    (__attribute__((address_space(3))) void*)(l), 16, 0, 0)

static __device__ __forceinline__ f32x4 mfma16(bf16x8 a, bf16x8 b, f32x4 c) {
  return __builtin_amdgcn_mfma_f32_16x16x32_bf16(a, b, c, 0, 0, 0);
}

// 2^x via v_exp_f32 (hardware base-2 exp)
static __device__ __forceinline__ float exp2_hw(float x) {
  return __builtin_amdgcn_exp2f(x);
}

// XOR-swizzled element index for 64-col bf16 tiles (128B rows) -- attn K/V
static __device__ __forceinline__ int swz64(int row, int col) {
  return (row * 64 + col) ^ ((row & 7) << 3);
}

// XOR-swizzle for 32-col bf16 tiles (64B rows) -- GEMM A/B: elem ^= ((row&3)<<3)
static __device__ __forceinline__ int swz32e(int e) {
  return e ^ (((e >> 5) & 3) << 3);
}

// fp32 -> bf16 for x, qkv_w, proj_w in one launch (dsts contiguous in ws)
__global__ __launch_bounds__(256) void cvt_all(const float* __restrict__ x,
                                               const float* __restrict__ wq,
                                               const float* __restrict__ wp,
                                               __bf16* __restrict__ dst,
                                               int nx4, int nwq4, int total4) {
  const int i = blockIdx.x * 256 + threadIdx.x;
  if (i >= total4) return;
  const float* src;
  int off;
  if (i < nx4) { src = x; off = i; }
  else if (i < nx4 + nwq4) { src = wq; off = i - nx4; }
  else { src = wp; off = i - nx4 - nwq4; }
  const float4 v = *(const float4*)&src[(size_t)off * 4];
  bf16x4 o;
  o[0] = (__bf16)v.x; o[1] = (__bf16)v.y; o[2] = (__bf16)v.z; o[3] = (__bf16)v.w;
  *(bf16x4*)&dst[(size_t)i * 4] = o;
}

// C[m,n] = sum_k A[m,k] * Bw[n,k] + bias[n]   (A, Bw bf16; bias fp32)
// Tile 128x128x32; 4 waves (2x2), each 64x64; 2-buf pipeline (STAGE t+1 after barrier,
// vmcnt(0) at top retires only tile t), 34.8KB LDS + launch_bounds(256,4) -> 4 blocks/CU.
// LDS tiles XOR-swizzled (byte ^= (row&3)<<4): linear gll-dest + pre-swizzled source col
// + swizzled ds_read (rule #21) -- kills the 8-way bank conflict of 64B-row b128 reads.
// EPI==0: scatter Q*(0.125*log2e)[bh][l][d], K[bh][l][d]; V-blocks transpose via LDS -> Vt[bh][d][l]
// EPI==1: out[m*N + n] row-major fp32
template <int EPI>
__global__ __launch_bounds__(256, 4) void gemm_nt(const __bf16* __restrict__ A,
                                                  const __bf16* __restrict__ Bw,
                                                  const float* __restrict__ bias,
                                                  float* __restrict__ out,
                                                  __bf16* __restrict__ Qb,
                                                  __bf16* __restrict__ Kb,
                                                  __bf16* __restrict__ Vtb,
                                                  int M, int N, int K) {
  // A bufs: [0,4096),[4096,8192); B bufs: [8192,12288),[12288,16384).
  // V-epilogue transpose tile [128][136] = 17408 elems (34816 B) reuses the whole region.
  __shared__ alignas(16) __bf16 smem[17408];
  const int tid = threadIdx.x;
  const int lane = tid & 63;
  const int wave = tid >> 6;
  const int wr = wave >> 1, wc = wave & 1;
  const int l15 = lane & 15, lhi = lane >> 4;
  const int mbase = blockIdx.x * 128;
  const int nbase = blockIdx.y * 128;

  f32x4 acc[4][4];
#pragma unroll
  for (int m = 0; m < 4; ++m)
#pragma unroll
    for (int n = 0; n < 4; ++n) acc[m][n] = (f32x4){0.f, 0.f, 0.f, 0.f};

  const int e0 = wave * 512 + lane * 8;  // linear LDS dest elem (16B/lane)
  const int e1 = e0 + 2048;
  // pre-swizzled SOURCE position: row bits unchanged, col ^= ((row&3)<<3)
  const int le0 = swz32e(e0), le1 = swz32e(e1);
  const int ar0 = mbase + (le0 >> 5), ac0 = le0 & 31;
  const int ar1 = mbase + (le1 >> 5), ac1 = le1 & 31;
  const int br0 = nbase + (le0 >> 5);
  const int br1 = nbase + (le1 >> 5);

  const int nkt = K >> 5;

#define STAGE(t, bf) do { \
    const int kb_ = (t) << 5; \
    GLL16(A + (size_t)ar0 * K + kb_ + ac0, &smem[(bf) * 4096 + e0]); \
    GLL16(A + (size_t)ar1 * K + kb_ + ac1, &smem[(bf) * 4096 + e1]); \
    GLL16(Bw + (size_t)br0 * K + kb_ + ac0, &smem[8192 + (bf) * 4096 + e0]); \
    GLL16(Bw + (size_t)br1 * K + kb_ + ac1, &smem[8192 + (bf) * 4096 + e1]); \
  } while (0)

  // prologue: tile 0 in flight
  STAGE(0, 0);

  for (int kt = 0; kt < nkt; ++kt) {
    const int cur = kt & 1;
    // only tile kt's 4 loads are outstanding here (kt+1 issued after the barrier)
    asm volatile("s_waitcnt vmcnt(0)" ::: "memory");
    __builtin_amdgcn_s_barrier();
    asm volatile("" ::: "memory");
    if (kt + 1 < nkt) STAGE(kt + 1, cur ^ 1);  // latency hides under this iter's MFMA

    const __bf16* bufA = &smem[cur * 4096];
    const __bf16* bufB = &smem[8192 + cur * 4096];
    bf16x8 a[4], b[4];
#pragma unroll
    for (int m = 0; m < 4; ++m)
      a[m] = *(const bf16x8*)&bufA[swz32e((wr * 64 + m * 16 + l15) * 32 + lhi * 8)];
#pragma unroll
    for (int n = 0; n < 4; ++n)
      b[n] = *(const bf16x8*)&bufB[swz32e((wc * 64 + n * 16 + l15) * 32 + lhi * 8)];
#pragma unroll
    for (int m = 0; m < 4; ++m)
#pragma unroll
      for (int n = 0; n < 4; ++n)
        acc[m][n] = mfma16(a[m], b[n], acc[m][n]);
  }
#undef STAGE

  // ---------------- epilogue ----------------
  if (EPI == 0 && nbase >= 1536) {
    // V block: transpose via LDS, coalesced Vt[bh][d][l] stores.
    __syncthreads();  // all staging reads done; reuse smem
    __bf16* ldsT = &smem[0];  // [128 gcol][stride 136] bf16 = 34816 B
#pragma unroll
    for (int n = 0; n < 4; ++n) {
      const int gl = wc * 64 + n * 16 + l15;
      const float bv = bias[nbase + gl];
#pragma unroll
      for (int m = 0; m < 4; ++m) {
        bf16x4 pk;
#pragma unroll
        for (int i = 0; i < 4; ++i) pk[i] = (__bf16)(acc[m][n][i] + bv);
        *(bf16x4*)&ldsT[gl * 136 + wr * 64 + m * 16 + lhi * 4] = pk;
      }
    }
    __syncthreads();
    // read back rows (gcol-major) and store contiguous lrow runs
    const int r = tid >> 1;        // 0..127  (local gcol)
    const int half = tid & 1;      // 0..1    (which 64-lrow half)
    const int head = ((nbase - 1536) >> 6) + (r >> 6);
    const int d = r & 63;
    const int bb = mbase >> 10;
    const int lbase = mbase & 1023;  // row offset within this batch's L
    __bf16* dst = Vtb + ((size_t)(bb * 12 + head) * 64 + d) * 1024 + lbase + half * 64;
    const __bf16* srcl = &ldsT[r * 136 + half * 64];
#pragma unroll
    for (int j = 0; j < 8; ++j)
      *(bf16x8*)&dst[j * 8] = *(const bf16x8*)&srcl[j * 8];
    return;
  }

  // C/D layout row=(lane>>4)*4+i, col=lane&15
#pragma unroll
  for (int n = 0; n < 4; ++n) {
    const int gcol = nbase + wc * 64 + n * 16 + l15;
    const float bv = bias[gcol];
    if (EPI == 1) {
#pragma unroll
      for (int m = 0; m < 4; ++m)
#pragma unroll
        for (int i = 0; i < 4; ++i) {
          const int grow = mbase + wr * 64 + m * 16 + lhi * 4 + i;
          out[(size_t)grow * N + gcol] = acc[m][n][i] + bv;
        }
    } else {
      const int three = gcol / 768;   // 0 or 1 here (V handled above)
      const int rem = gcol - three * 768;
      const int head = rem >> 6;
      const int d = rem & 63;
#pragma unroll
      for (int m = 0; m < 4; ++m)
#pragma unroll
        for (int i = 0; i < 4; ++i) {
          const int grow = mbase + wr * 64 + m * 16 + lhi * 4 + i;
          const int bb = grow >> 10;     // batch
          const int lrow = grow & 1023;  // position in L
          const int bh = bb * 12 + head;
          const float v = acc[m][n][i] + bv;
          if (three == 0)
            Qb[((size_t)bh * 1024 + lrow) * 64 + d] = (__bf16)(v * 0.18033688f);  // hd^-0.5 * log2(e)
          else
            Kb[((size_t)bh * 1024 + lrow) * 64 + d] = (__bf16)v;
        }
    }
  }
}

// Flash attention: grid (96 bh, 8 q-tiles), block 512 = 8 waves; wave owns 16 q-rows x 64 d.
// 24 waves/CU (3 blocks x 8 waves, LDS 51200B) for latency hiding.
// Swapped QK^T (S^T = K*Q^T) so softmax is lane-local; base-2 exp (log2e folded into Q);
// defer-max rescale (THR=8); packed b64 P writes; K/V double-buffered + XOR-swizzled.
__global__ __launch_bounds__(512, 6) void attn_fwd(const __bf16* __restrict__ Q,
                                                   const __bf16* __restrict__ Kg,
                                                   const __bf16* __restrict__ Vt,
                                                   __bf16* __restrict__ O) {
  __shared__ alignas(16) __bf16 lK[2][64 * 64];     // [key][d] swizzled
  __shared__ alignas(16) __bf16 lV[2][64 * 64];     // [d][key] swizzled
  __shared__ alignas(16) __bf16 lP[8][16 * 72];     // per-wave P [qrow][key], padded stride 72
  const int tid = threadIdx.x, lane = tid & 63, wave = tid >> 6;  // wave 0..7
  const int l15 = lane & 15, lhi = lane >> 4;
  const int bh = blockIdx.x, qt = blockIdx.y;  // bh on x: XCD L2 reuse (96 % 8 == 0)
  const int b = bh / 12, head = bh % 12;

  // Q fragment as MFMA B-operand (out-col = qrow): qrow = wave*16+l15, k = kk*32+lhi*8
  bf16x8 q[2];
  {
    const int qrow = qt * 128 + wave * 16 + l15;
#pragma unroll
    for (int kk = 0; kk < 2; ++kk)
      q[kk] = *(const bf16x8*)&Q[((size_t)bh * 1024 + qrow) * 64 + kk * 32 + lhi * 8];
  }

  f32x4 o[4];
  float mrun = -3.0e38f, lrun = 0.f;
#pragma unroll
  for (int n = 0; n < 4; ++n) o[n] = (f32x4){0.f, 0.f, 0.f, 0.f};

  // staging lane constants: 512 threads x 16B = full 8KB tile in one GLL16 each
  const int q0b = tid * 16;                        // LDS byte slot
  const int p0b = q0b ^ (((q0b >> 7) & 7) << 4);   // pre-swizzled source position
  const int e0 = q0b >> 1;                         // linear LDS elem dest
  const int kofs0 = p0b >> 1;                      // K tile contiguous 64x64
  const int vofs0 = (p0b >> 7) * 1024 + ((p0b & 127) >> 1);  // V rows stride 1024

  const __bf16* kbase = Kg + (size_t)bh * 1024 * 64;
  const __bf16* vbase = Vt + (size_t)bh * 64 * 1024;

  GLL16(kbase + kofs0, &lK[0][e0]);
  GLL16(vbase + vofs0, &lV[0][e0]);
  __syncthreads();

  for (int kv = 0; kv < 16; ++kv) {
    const int cur = kv & 1;
    if (kv + 1 < 16) {
      GLL16(kbase + (kv + 1) * 4096 + kofs0, &lK[cur ^ 1][e0]);
      GLL16(vbase + (kv + 1) * 64 + vofs0, &lV[cur ^ 1][e0]);
    }

    // S^T = K Q^T (log2-scaled): s[km][i] -> key = km*16+lhi*4+i, qrow = l15
    f32x4 s[4];
#pragma unroll
    for (int km = 0; km < 4; ++km) {
      bf16x8 k0 = *(const bf16x8*)&lK[cur][swz64(km * 16 + l15, lhi * 8)];
      bf16x8 k1 = *(const bf16x8*)&lK[cur][swz64(km * 16 + l15, 32 + lhi * 8)];
      f32x4 z = (f32x4){0.f, 0.f, 0.f, 0.f};
      z = mfma16(k0, q[0], z);
      z = mfma16(k1, q[1], z);
      s[km] = z;
    }

    // local max over this lane's 16 keys
    float lm = s[0][0];
#pragma unroll
    for (int km = 0; km < 4; ++km)
#pragma unroll
      for (int i = 0; i < 4; ++i) lm = fmaxf(lm, s[km][i]);

    // defer-max: only rescale when max grew by > 8 (base-2 units); P bounded by 2^8
    if (!__all(lm - mrun <= 8.f)) {
      float r = lm;
      r = fmaxf(r, __shfl_xor(r, 16));
      r = fmaxf(r, __shfl_xor(r, 32));
      const float mnew = fmaxf(mrun, r);
      const float alpha = exp2_hw(mrun - mnew);
      mrun = mnew;
      lrun *= alpha;
      // distribute alpha to O-rows: o[n][i] has qrow wave*16+lhi*4+i -> alpha at lane lhi*4+i
      float am[4];
#pragma unroll
      for (int i = 0; i < 4; ++i) am[i] = __shfl(alpha, (lhi << 2) | i, 64);
#pragma unroll
      for (int n = 0; n < 4; ++n)
#pragma unroll
        for (int i = 0; i < 4; ++i) o[n][i] *= am[i];
    }

    // P = 2^(s - m), packed b64 writes into lP[qrow][key]
    {
      float ps = 0.f;
#pragma unroll
      for (int km = 0; km < 4; ++km) {
        bf16x4 pk;
#pragma unroll
        for (int i = 0; i < 4; ++i) {
          const float p = exp2_hw(s[km][i] - mrun);
          ps += p;
          pk[i] = (__bf16)p;
        }
        *(bf16x4*)&lP[wave][l15 * 72 + km * 16 + lhi * 4] = pk;
      }
      lrun += ps;  // per-lane partial (16 keys); reduced across lhi at end
    }

    // O += P V
    bf16x8 vf[4][2];
#pragma unroll
    for (int n = 0; n < 4; ++n)
#pragma unroll
      for (int kk = 0; kk < 2; ++kk)
        vf[n][kk] = *(const bf16x8*)&lV[cur][swz64(n * 16 + l15, kk * 32 + lhi * 8)];
    {
      bf16x8 p0 = *(const bf16x8*)&lP[wave][l15 * 72 + lhi * 8];
      bf16x8 p1 = *(const bf16x8*)&lP[wave][l15 * 72 + 32 + lhi * 8];
#pragma unroll
      for (int n = 0; n < 4; ++n) {
        o[n] = mfma16(p0, vf[n][0], o[n]);
        o[n] = mfma16(p1, vf[n][1], o[n]);
      }
    }
    __syncthreads();  // single barrier/iter: drains prefetch, protects buffers
  }

  // epilogue: finish denominator (reduce across lhi), distribute, write
  float r = lrun;
  r += __shfl_xor(r, 16);
  r += __shfl_xor(r, 32);
  const float inv = 1.f / r;
  float im[4];
#pragma unroll
  for (int i = 0; i < 4; ++i) im[i] = __shfl(inv, (lhi << 2) | i, 64);
#pragma unroll
  for (int i = 0; i < 4; ++i) {
    const int lrow = qt * 128 + wave * 16 + lhi * 4 + i;
#pragma unroll
    for (int n = 0; n < 4; ++n) {
      const int col = head * 64 + n * 16 + l15;
      O[((size_t)b * 1024 + lrow) * 768 + col] = (__bf16)(o[n][i] * im[i]);
    }
  }
}

extern "C" void kernel_launch(void* const* d_in, const int* in_sizes, int n_in,
                              void* d_out, int out_size, void* d_ws, size_t ws_size,
                              hipStream_t stream) {
  const float* x = (const float*)d_in[0];
  const float* qkv_w = (const float*)d_in[1];
  const float* qkv_b = (const float*)d_in[2];
  const float* proj_w = (const float*)d_in[3];
  const float* proj_b = (const float*)d_in[4];
  float* out = (float*)d_out;

  const size_t NX = (size_t)8192 * 768;
  const size_t NWQ = (size_t)2304 * 768;
  const size_t NWP = (size_t)768 * 768;
  const size_t SZ = (size_t)96 * 1024 * 64;

  __bf16* xb = (__bf16*)d_ws;
  __bf16* wqkvb = xb + NX;
  __bf16* wprojb = wqkvb + NWQ;
  __bf16* Q = wprojb + NWP;
  __bf16* K = Q + SZ;
  __bf16* Vt = K + SZ;
  __bf16* AO = Vt + SZ;

  const int nx4 = (int)(NX / 4), nwq4 = (int)(NWQ / 4), nwp4 = (int)(NWP / 4);
  const int total4 = nx4 + nwq4 + nwp4;
  cvt_all<<<(total4 + 255) / 256, 256, 0, stream>>>(x, qkv_w, proj_w, xb, nx4, nwq4, total4);

  gemm_nt<0><<<dim3(64, 18), 256, 0, stream>>>(xb, wqkvb, qkv_b, nullptr, Q, K, Vt,
                                               8192, 2304, 768);
  attn_fwd<<<dim3(96, 8), 512, 0, stream>>>(Q, K, Vt, AO);
  gemm_nt<1><<<dim3(64, 6), 256, 0, stream>>>(AO, wprojb, proj_b, out,
                                              nullptr, nullptr, nullptr, 8192, 768, 768);
}

// Round 22
// 107.890 us; speedup vs baseline: 1.0788x; 1.0788x over previous
//
#include <hip/hip_runtime.h>

// Global attention block: x(8,32,32,768) fp32 -> qkv(2304) -> 12-head attn (L=1024, hd=64) -> proj(768) fp32
// Device I/O fp32; internal compute bf16 MFMA with fp32 accumulation.

typedef __attribute__((ext_vector_type(8))) __bf16 bf16x8;
typedef __attribute__((ext_vector_type(4))) __bf16 bf16x4;
typedef __attribute__((ext_vector_type(4))) float f32x4;

#define GLL16(g, l) __builtin_amdgcn_global_load_lds( \
    (const __attribute__((address_space(1))) void*)(g), \
    (__attribute__((address_space(3))) void*)(l), 16, 0, 0)

static __device__ __forceinline__ f32x4 mfma16(bf16x8 a, bf16x8 b, f32x4 c) {
  return __builtin_amdgcn_mfma_f32_16x16x32_bf16(a, b, c, 0, 0, 0);
}

// 2^x via v_exp_f32 (hardware base-2 exp)
static __device__ __forceinline__ float exp2_hw(float x) {
  return __builtin_amdgcn_exp2f(x);
}

// XOR-swizzle for 64-col bf16 tiles (128B rows): elem ^= ((row&7)<<3). Involution,
// row bits (>=6) unchanged. Spreads a wave's b128 reads across all 8 16B-windows (floor).
static __device__ __forceinline__ int swz64(int row, int col) {
  return (row * 64 + col) ^ ((row & 7) << 3);
}
static __device__ __forceinline__ int swz64e(int e) {
  return e ^ (((e >> 6) & 7) << 3);
}

// fp32 -> bf16 for x, qkv_w, proj_w in one launch (dsts contiguous in ws)
__global__ __launch_bounds__(256) void cvt_all(const float* __restrict__ x,
                                               const float* __restrict__ wq,
                                               const float* __restrict__ wp,
                                               __bf16* __restrict__ dst,
                                               int nx4, int nwq4, int total4) {
  const int i = blockIdx.x * 256 + threadIdx.x;
  if (i >= total4) return;
  const float* src;
  int off;
  if (i < nx4) { src = x; off = i; }
  else if (i < nx4 + nwq4) { src = wq; off = i - nx4; }
  else { src = wp; off = i - nx4 - nwq4; }
  const float4 v = *(const float4*)&src[(size_t)off * 4];
  bf16x4 o;
  o[0] = (__bf16)v.x; o[1] = (__bf16)v.y; o[2] = (__bf16)v.z; o[3] = (__bf16)v.w;
  *(bf16x4*)&dst[(size_t)i * 4] = o;
}

// C[m,n] = sum_k A[m,k] * Bw[n,k] + bias[n]   (A, Bw bf16; bias fp32)
// Tile 128x128x64 (BK=64): 4 waves (2x2), each 64x64; 32 MFMA per barrier (2x R19).
// 2-buf pipeline (STAGE t+1 after barrier; vmcnt(0) at top retires only tile t).
// LDS 64KB -> 2 blocks/CU, launch_bounds(256,2). Tiles swz64-swizzled: linear GLL dest +
// pre-swizzled source col + swizzled ds_read (rule #21) -> b128 reads at the 8-slot floor.
// EPI==0: scatter Q*(0.125*log2e)[bh][l][d], K[bh][l][d]; V-blocks transpose via LDS -> Vt[bh][d][l]
// EPI==1: out[m*N + n] row-major fp32
template <int EPI>
__global__ __launch_bounds__(256, 2) void gemm_nt(const __bf16* __restrict__ A,
                                                  const __bf16* __restrict__ Bw,
                                                  const float* __restrict__ bias,
                                                  float* __restrict__ out,
                                                  __bf16* __restrict__ Qb,
                                                  __bf16* __restrict__ Kb,
                                                  __bf16* __restrict__ Vtb,
                                                  int M, int N, int K) {
  // A bufs: [0,8192),[8192,16384); B bufs: [16384,24576),[24576,32768) (elems).
  // V-epilogue transpose tile [128][136] = 17408 elems reuses the front.
  __shared__ alignas(16) __bf16 smem[32768];
  const int tid = threadIdx.x;
  const int lane = tid & 63;
  const int wave = tid >> 6;
  const int wr = wave >> 1, wc = wave & 1;
  const int l15 = lane & 15, lhi = lane >> 4;
  const int mbase = blockIdx.x * 128;
  const int nbase = blockIdx.y * 128;

  f32x4 acc[4][4];
#pragma unroll
  for (int m = 0; m < 4; ++m)
#pragma unroll
    for (int n = 0; n < 4; ++n) acc[m][n] = (f32x4){0.f, 0.f, 0.f, 0.f};

  // staging: 128x64 tile = 8192 elems = 4 chunks of 2048; dest chunk-linear (16B/lane),
  // source position pre-swizzled (row bits unchanged -> contiguous row segment).
  int srow[4], scol[4];
#pragma unroll
  for (int c = 0; c < 4; ++c) {
    const int e = c * 2048 + tid * 8;
    const int se = swz64e(e);
    srow[c] = se >> 6;   // 0..127
    scol[c] = se & 63;
  }
  const int eD = tid * 8;  // dest offset within each chunk

  const int nkt = K >> 6;  // BK = 64

#define STAGE(t, bf) do { \
    const int kb_ = (t) << 6; \
    GLL16(A + (size_t)(mbase + srow[0]) * K + kb_ + scol[0], &smem[(bf) * 8192 + 0 * 2048 + eD]); \
    GLL16(A + (size_t)(mbase + srow[1]) * K + kb_ + scol[1], &smem[(bf) * 8192 + 1 * 2048 + eD]); \
    GLL16(A + (size_t)(mbase + srow[2]) * K + kb_ + scol[2], &smem[(bf) * 8192 + 2 * 2048 + eD]); \
    GLL16(A + (size_t)(mbase + srow[3]) * K + kb_ + scol[3], &smem[(bf) * 8192 + 3 * 2048 + eD]); \
    GLL16(Bw + (size_t)(nbase + srow[0]) * K + kb_ + scol[0], &smem[16384 + (bf) * 8192 + 0 * 2048 + eD]); \
    GLL16(Bw + (size_t)(nbase + srow[1]) * K + kb_ + scol[1], &smem[16384 + (bf) * 8192 + 1 * 2048 + eD]); \
    GLL16(Bw + (size_t)(nbase + srow[2]) * K + kb_ + scol[2], &smem[16384 + (bf) * 8192 + 2 * 2048 + eD]); \
    GLL16(Bw + (size_t)(nbase + srow[3]) * K + kb_ + scol[3], &smem[16384 + (bf) * 8192 + 3 * 2048 + eD]); \
  } while (0)

  // prologue: tile 0 in flight
  STAGE(0, 0);

  for (int kt = 0; kt < nkt; ++kt) {
    const int cur = kt & 1;
    // only tile kt's 8 loads are outstanding here (kt+1 issued after the barrier)
    asm volatile("s_waitcnt vmcnt(0)" ::: "memory");
    __builtin_amdgcn_s_barrier();
    asm volatile("" ::: "memory");
    if (kt + 1 < nkt) STAGE(kt + 1, cur ^ 1);  // latency hides under this iter's 32 MFMA

    const __bf16* bufA = &smem[cur * 8192];
    const __bf16* bufB = &smem[16384 + cur * 8192];
#pragma unroll
    for (int kk = 0; kk < 2; ++kk) {
      bf16x8 a[4], b[4];
#pragma unroll
      for (int m = 0; m < 4; ++m)
        a[m] = *(const bf16x8*)&bufA[swz64(wr * 64 + m * 16 + l15, kk * 32 + lhi * 8)];
#pragma unroll
      for (int n = 0; n < 4; ++n)
        b[n] = *(const bf16x8*)&bufB[swz64(wc * 64 + n * 16 + l15, kk * 32 + lhi * 8)];
#pragma unroll
      for (int m = 0; m < 4; ++m)
#pragma unroll
        for (int n = 0; n < 4; ++n)
          acc[m][n] = mfma16(a[m], b[n], acc[m][n]);
    }
  }
#undef STAGE

  // ---------------- epilogue ----------------
  if (EPI == 0 && nbase >= 1536) {
    // V block: transpose via LDS, coalesced Vt[bh][d][l] stores.
    __syncthreads();  // all staging reads done; reuse smem
    __bf16* ldsT = &smem[0];  // [128 gcol][stride 136] bf16 = 34816 B
#pragma unroll
    for (int n = 0; n < 4; ++n) {
      const int gl = wc * 64 + n * 16 + l15;
      const float bv = bias[nbase + gl];
#pragma unroll
      for (int m = 0; m < 4; ++m) {
        bf16x4 pk;
#pragma unroll
        for (int i = 0; i < 4; ++i) pk[i] = (__bf16)(acc[m][n][i] + bv);
        *(bf16x4*)&ldsT[gl * 136 + wr * 64 + m * 16 + lhi * 4] = pk;
      }
    }
    __syncthreads();
    // read back rows (gcol-major) and store contiguous lrow runs
    const int r = tid >> 1;        // 0..127  (local gcol)
    const int half = tid & 1;      // 0..1    (which 64-lrow half)
    const int head = ((nbase - 1536) >> 6) + (r >> 6);
    const int d = r & 63;
    const int bb = mbase >> 10;
    const int lbase = mbase & 1023;  // row offset within this batch's L
    __bf16* dst = Vtb + ((size_t)(bb * 12 + head) * 64 + d) * 1024 + lbase + half * 64;
    const __bf16* srcl = &ldsT[r * 136 + half * 64];
#pragma unroll
    for (int j = 0; j < 8; ++j)
      *(bf16x8*)&dst[j * 8] = *(const bf16x8*)&srcl[j * 8];
    return;
  }

  // C/D layout row=(lane>>4)*4+i, col=lane&15
#pragma unroll
  for (int n = 0; n < 4; ++n) {
    const int gcol = nbase + wc * 64 + n * 16 + l15;
    const float bv = bias[gcol];
    if (EPI == 1) {
#pragma unroll
      for (int m = 0; m < 4; ++m)
#pragma unroll
        for (int i = 0; i < 4; ++i) {
          const int grow = mbase + wr * 64 + m * 16 + lhi * 4 + i;
          out[(size_t)grow * N + gcol] = acc[m][n][i] + bv;
        }
    } else {
      const int three = gcol / 768;   // 0 or 1 here (V handled above)
      const int rem = gcol - three * 768;
      const int head = rem >> 6;
      const int d = rem & 63;
#pragma unroll
      for (int m = 0; m < 4; ++m)
#pragma unroll
        for (int i = 0; i < 4; ++i) {
          const int grow = mbase + wr * 64 + m * 16 + lhi * 4 + i;
          const int bb = grow >> 10;     // batch
          const int lrow = grow & 1023;  // position in L
          const int bh = bb * 12 + head;
          const float v = acc[m][n][i] + bv;
          if (three == 0)
            Qb[((size_t)bh * 1024 + lrow) * 64 + d] = (__bf16)(v * 0.18033688f);  // hd^-0.5 * log2(e)
          else
            Kb[((size_t)bh * 1024 + lrow) * 64 + d] = (__bf16)v;
        }
    }
  }
}

// Flash attention: grid (96 bh, 8 q-tiles), block 512 = 8 waves; wave owns 16 q-rows x 64 d.
// 24 waves/CU (3 blocks x 8 waves, LDS 51200B) for latency hiding.
// Swapped QK^T (S^T = K*Q^T) so softmax is lane-local; base-2 exp (log2e folded into Q);
// defer-max rescale (THR=8); packed b64 P writes; K/V double-buffered + XOR-swizzled.
__global__ __launch_bounds__(512, 6) void attn_fwd(const __bf16* __restrict__ Q,
                                                   const __bf16* __restrict__ Kg,
                                                   const __bf16* __restrict__ Vt,
                                                   __bf16* __restrict__ O) {
  __shared__ alignas(16) __bf16 lK[2][64 * 64];     // [key][d] swizzled
  __shared__ alignas(16) __bf16 lV[2][64 * 64];     // [d][key] swizzled
  __shared__ alignas(16) __bf16 lP[8][16 * 72];     // per-wave P [qrow][key], padded stride 72
  const int tid = threadIdx.x, lane = tid & 63, wave = tid >> 6;  // wave 0..7
  const int l15 = lane & 15, lhi = lane >> 4;
  const int bh = blockIdx.x, qt = blockIdx.y;  // bh on x: XCD L2 reuse (96 % 8 == 0)
  const int b = bh / 12, head = bh % 12;

  // Q fragment as MFMA B-operand (out-col = qrow): qrow = wave*16+l15, k = kk*32+lhi*8
  bf16x8 q[2];
  {
    const int qrow = qt * 128 + wave * 16 + l15;
#pragma unroll
    for (int kk = 0; kk < 2; ++kk)
      q[kk] = *(const bf16x8*)&Q[((size_t)bh * 1024 + qrow) * 64 + kk * 32 + lhi * 8];
  }

  f32x4 o[4];
  float mrun = -3.0e38f, lrun = 0.f;
#pragma unroll
  for (int n = 0; n < 4; ++n) o[n] = (f32x4){0.f, 0.f, 0.f, 0.f};

  // staging lane constants: 512 threads x 16B = full 8KB tile in one GLL16 each
  const int q0b = tid * 16;                        // LDS byte slot
  const int p0b = q0b ^ (((q0b >> 7) & 7) << 4);   // pre-swizzled source position
  const int e0 = q0b >> 1;                         // linear LDS elem dest
  const int kofs0 = p0b >> 1;                      // K tile contiguous 64x64
  const int vofs0 = (p0b >> 7) * 1024 + ((p0b & 127) >> 1);  // V rows stride 1024

  const __bf16* kbase = Kg + (size_t)bh * 1024 * 64;
  const __bf16* vbase = Vt + (size_t)bh * 64 * 1024;

  GLL16(kbase + kofs0, &lK[0][e0]);
  GLL16(vbase + vofs0, &lV[0][e0]);
  __syncthreads();

  for (int kv = 0; kv < 16; ++kv) {
    const int cur = kv & 1;
    if (kv + 1 < 16) {
      GLL16(kbase + (kv + 1) * 4096 + kofs0, &lK[cur ^ 1][e0]);
      GLL16(vbase + (kv + 1) * 64 + vofs0, &lV[cur ^ 1][e0]);
    }

    // S^T = K Q^T (log2-scaled): s[km][i] -> key = km*16+lhi*4+i, qrow = l15
    f32x4 s[4];
#pragma unroll
    for (int km = 0; km < 4; ++km) {
      bf16x8 k0 = *(const bf16x8*)&lK[cur][swz64(km * 16 + l15, lhi * 8)];
      bf16x8 k1 = *(const bf16x8*)&lK[cur][swz64(km * 16 + l15, 32 + lhi * 8)];
      f32x4 z = (f32x4){0.f, 0.f, 0.f, 0.f};
      z = mfma16(k0, q[0], z);
      z = mfma16(k1, q[1], z);
      s[km] = z;
    }

    // local max over this lane's 16 keys
    float lm = s[0][0];
#pragma unroll
    for (int km = 0; km < 4; ++km)
#pragma unroll
      for (int i = 0; i < 4; ++i) lm = fmaxf(lm, s[km][i]);

    // defer-max: only rescale when max grew by > 8 (base-2 units); P bounded by 2^8
    if (!__all(lm - mrun <= 8.f)) {
      float r = lm;
      r = fmaxf(r, __shfl_xor(r, 16));
      r = fmaxf(r, __shfl_xor(r, 32));
      const float mnew = fmaxf(mrun, r);
      const float alpha = exp2_hw(mrun - mnew);
      mrun = mnew;
      lrun *= alpha;
      // distribute alpha to O-rows: o[n][i] has qrow wave*16+lhi*4+i -> alpha at lane lhi*4+i
      float am[4];
#pragma unroll
      for (int i = 0; i < 4; ++i) am[i] = __shfl(alpha, (lhi << 2) | i, 64);
#pragma unroll
      for (int n = 0; n < 4; ++n)
#pragma unroll
        for (int i = 0; i < 4; ++i) o[n][i] *= am[i];
    }

    // P = 2^(s - m), packed b64 writes into lP[qrow][key]
    {
      float ps = 0.f;
#pragma unroll
      for (int km = 0; km < 4; ++km) {
        bf16x4 pk;
#pragma unroll
        for (int i = 0; i < 4; ++i) {
          const float p = exp2_hw(s[km][i] - mrun);
          ps += p;
          pk[i] = (__bf16)p;
        }
        *(bf16x4*)&lP[wave][l15 * 72 + km * 16 + lhi * 4] = pk;
      }
      lrun += ps;  // per-lane partial (16 keys); reduced across lhi at end
    }

    // O += P V
    bf16x8 vf[4][2];
#pragma unroll
    for (int n = 0; n < 4; ++n)
#pragma unroll
      for (int kk = 0; kk < 2; ++kk)
        vf[n][kk] = *(const bf16x8*)&lV[cur][swz64(n * 16 + l15, kk * 32 + lhi * 8)];
    {
      bf16x8 p0 = *(const bf16x8*)&lP[wave][l15 * 72 + lhi * 8];
      bf16x8 p1 = *(const bf16x8*)&lP[wave][l15 * 72 + 32 + lhi * 8];
#pragma unroll
      for (int n = 0; n < 4; ++n) {
        o[n] = mfma16(p0, vf[n][0], o[n]);
        o[n] = mfma16(p1, vf[n][1], o[n]);
      }
    }
    __syncthreads();  // single barrier/iter: drains prefetch, protects buffers
  }

  // epilogue: finish denominator (reduce across lhi), distribute, write
  float r = lrun;
  r += __shfl_xor(r, 16);
  r += __shfl_xor(r, 32);
  const float inv = 1.f / r;
  float im[4];
#pragma unroll
  for (int i = 0; i < 4; ++i) im[i] = __shfl(inv, (lhi << 2) | i, 64);
#pragma unroll
  for (int i = 0; i < 4; ++i) {
    const int lrow = qt * 128 + wave * 16 + lhi * 4 + i;
#pragma unroll
    for (int n = 0; n < 4; ++n) {
      const int col = head * 64 + n * 16 + l15;
      O[((size_t)b * 1024 + lrow) * 768 + col] = (__bf16)(o[n][i] * im[i]);
    }
  }
}

extern "C" void kernel_launch(void* const* d_in, const int* in_sizes, int n_in,
                              void* d_out, int out_size, void* d_ws, size_t ws_size,
                              hipStream_t stream) {
  const float* x = (const float*)d_in[0];
  const float* qkv_w = (const float*)d_in[1];
  const float* qkv_b = (const float*)d_in[2];
  const float* proj_w = (const float*)d_in[3];
  const float* proj_b = (const float*)d_in[4];
  float* out = (float*)d_out;

  const size_t NX = (size_t)8192 * 768;
  const size_t NWQ = (size_t)2304 * 768;
  const size_t NWP = (size_t)768 * 768;
  const size_t SZ = (size_t)96 * 1024 * 64;

  __bf16* xb = (__bf16*)d_ws;
  __bf16* wqkvb = xb + NX;
  __bf16* wprojb = wqkvb + NWQ;
  __bf16* Q = wprojb + NWP;
  __bf16* K = Q + SZ;
  __bf16* Vt = K + SZ;
  __bf16* AO = Vt + SZ;

  const int nx4 = (int)(NX / 4), nwq4 = (int)(NWQ / 4), nwp4 = (int)(NWP / 4);
  const int total4 = nx4 + nwq4 + nwp4;
  cvt_all<<<(total4 + 255) / 256, 256, 0, stream>>>(x, qkv_w, proj_w, xb, nx4, nwq4, total4);

  gemm_nt<0><<<dim3(64, 18), 256, 0, stream>>>(xb, wqkvb, qkv_b, nullptr, Q, K, Vt,
                                               8192, 2304, 768);
  attn_fwd<<<dim3(96, 8), 512, 0, stream>>>(Q, K, Vt, AO);
  gemm_nt<1><<<dim3(64, 6), 256, 0, stream>>>(AO, wprojb, proj_b, out,
                                              nullptr, nullptr, nullptr, 8192, 768, 768);
}